// Round 16
// baseline (545.015 us; speedup 1.0000x reference)
//
#include <hip/hip_runtime.h>

// ---------------- problem constants ----------------
#define S_LEN 2048
#define HD    4096
#define NH    32
#define NKV   8
#define DH    128
#define NQKV  6144          // 4096 Q + 1024 K + 1024 V
#define QKV_STRIDE_B (NQKV * 2)

typedef __bf16 bf16_t;
typedef __bf16 bf16x8 __attribute__((ext_vector_type(8)));
typedef float  f32x4  __attribute__((ext_vector_type(4)));

// ---------------- helpers ----------------
__device__ inline unsigned short f2bf_bits(float f) {
  unsigned int u = __builtin_bit_cast(unsigned int, f);
  unsigned int r = (u + 0x7FFFu + ((u >> 16) & 1u)) >> 16;  // RNE
  return (unsigned short)r;
}
__device__ inline bf16_t f2bf(float f) {
  return __builtin_bit_cast(bf16_t, f2bf_bits(f));
}
__device__ inline float bf2f(bf16_t b) {
  unsigned int u = ((unsigned int)__builtin_bit_cast(unsigned short, b)) << 16;
  return __builtin_bit_cast(float, u);
}
__device__ inline bf16x8 cvt8(float4 a, float4 b) {
  bf16x8 o;
  o[0] = f2bf(a.x); o[1] = f2bf(a.y); o[2] = f2bf(a.z); o[3] = f2bf(a.w);
  o[4] = f2bf(b.x); o[5] = f2bf(b.y); o[6] = f2bf(b.z); o[7] = f2bf(b.w);
  return o;
}

__device__ inline void load_lds16(const void* g, void* l) {
  __builtin_amdgcn_global_load_lds(
      (__attribute__((address_space(1))) unsigned int*)(void*)g,
      (__attribute__((address_space(3))) unsigned int*)l, 16, 0, 0);
}

__device__ inline void store_out(float* p, float v)  { *p = v; }
__device__ inline void store_out(bf16_t* p, float v) { *p = f2bf(v); }

// ---------------- GEMM (QKV): C[M,n] = X[M,K](f32) * W[n,K]^T(f32), bf16 out --
// R13's verified db32 pipeline; staging replaced by reg-cvt with T14
// issue-early/write-late split. LDS dest identity is the DMA's definitional
// mapping (base + lane*16); source rows/cols are the verified R8 expressions
// translated to f32 element offsets. Reads/MFMA/epilogue byte-identical to R13.
__global__ __launch_bounds__(256)
void gemm_qkv_kernel(const float* __restrict__ X, const float* __restrict__ Wq,
                     const float* __restrict__ Wk, const float* __restrict__ Wv,
                     bf16_t* __restrict__ C, int M, int N, int K, int nbx) {
  __shared__ __align__(16) bf16_t lA[2][128 * 32];
  __shared__ __align__(16) bf16_t lB[2][128 * 32];
  const int t = threadIdx.x;
  const int lane = t & 63, wave = t >> 6;

  // bijective XCD-aware remap (verbatim R8)
  const int nwg = gridDim.x;
  const int orig = blockIdx.x;
  const int xcd = orig & 7;
  const int qq = nwg >> 3, rr = nwg & 7;
  const int base = (xcd < rr) ? xcd * (qq + 1) : rr * (qq + 1) + (xcd - rr) * qq;
  const int wgid = base + (orig >> 3);
  const int row0 = (wgid / nbx) * 128, col0 = (wgid % nbx) * 128;

  const int wm = (wave >> 1) * 64, wn = (wave & 1) * 64;

  // B matrix select (128-col stripe never crosses a weight boundary)
  const float* Bmat;
  int bc0;
  if (col0 < HD)            { Bmat = Wq; bc0 = col0; }
  else if (col0 < HD + 1024){ Bmat = Wk; bc0 = col0 - HD; }
  else                      { Bmat = Wv; bc0 = col0 - HD - 1024; }

  // staging geometry (R8 rows/cols, f32 element offsets)
  const int rA = wave * 32 + (lane >> 2);   // chunk rows rA, rA+16
  const int cE = (lane & 3) * 8;            // k-col element offset (8 elems/lane)
  const float* As0 = X    + (size_t)(row0 + rA) * K + cE;
  const float* As1 = X    + (size_t)(row0 + rA + 16) * K + cE;
  const float* Bs0 = Bmat + (size_t)(bc0 + rA) * K + cE;
  const float* Bs1 = Bmat + (size_t)(bc0 + rA + 16) * K + cE;

  const int fr = lane & 15, fq = lane >> 4;
  f32x4 acc[4][4] = {};

  auto ld4 = [&](const float* p) { return *reinterpret_cast<const float4*>(p); };
  auto wr = [&](int b, bf16_t* tile, int off, bf16x8 v) {
    *reinterpret_cast<bf16x8*>((char*)tile + wave * 2048 + off + lane * 16) = v;
  };

  // prologue: stage tile 0 (loads + writes, drained by first sync)
  {
    wr(0, lA[0], 0,    cvt8(ld4(As0), ld4(As0 + 4)));
    wr(0, lA[0], 1024, cvt8(ld4(As1), ld4(As1 + 4)));
    wr(0, lB[0], 0,    cvt8(ld4(Bs0), ld4(Bs0 + 4)));
    wr(0, lB[0], 1024, cvt8(ld4(Bs1), ld4(Bs1 + 4)));
  }

  int b = 0;
  for (int k0 = 0; k0 < K; k0 += 32) {
    __syncthreads();   // writes to buf drained; buf^1 readers done

    // issue-early: loads for tile T+1 (hide HBM latency under MFMA)
    float4 a00, a01, a10, a11, b00, b01, b10, b11;
    const bool more = (k0 + 32 < K);
    if (more) {
      const int e = k0 + 32;
      a00 = ld4(As0 + e); a01 = ld4(As0 + e + 4);
      a10 = ld4(As1 + e); a11 = ld4(As1 + e + 4);
      b00 = ld4(Bs0 + e); b01 = ld4(Bs0 + e + 4);
      b10 = ld4(Bs1 + e); b11 = ld4(Bs1 + e + 4);
    }

    // reads + MFMA (verbatim R13)
    bf16x8 af[4], bfv[4];
#pragma unroll
    for (int mi = 0; mi < 4; mi++)
      af[mi] = *reinterpret_cast<const bf16x8*>(&lA[b][(wm + mi * 16 + fr) * 32 + fq * 8]);
#pragma unroll
    for (int ni = 0; ni < 4; ni++)
      bfv[ni] = *reinterpret_cast<const bf16x8*>(&lB[b][(wn + ni * 16 + fr) * 32 + fq * 8]);
    __builtin_amdgcn_s_setprio(1);
#pragma unroll
    for (int mi = 0; mi < 4; mi++)
#pragma unroll
      for (int ni = 0; ni < 4; ni++)
        acc[mi][ni] = __builtin_amdgcn_mfma_f32_16x16x32_bf16(af[mi], bfv[ni], acc[mi][ni], 0, 0, 0);
    __builtin_amdgcn_s_setprio(0);

    // write-late: publish tile T+1 into buf^1 (visible after next sync)
    if (more) {
      wr(b ^ 1, lA[b ^ 1], 0,    cvt8(a00, a01));
      wr(b ^ 1, lA[b ^ 1], 1024, cvt8(a10, a11));
      wr(b ^ 1, lB[b ^ 1], 0,    cvt8(b00, b01));
      wr(b ^ 1, lB[b ^ 1], 1024, cvt8(b10, b11));
    }
    b ^= 1;
  }

  // epilogue (verbatim R8)
#pragma unroll
  for (int mi = 0; mi < 4; mi++) {
#pragma unroll
    for (int r = 0; r < 4; r++) {
      int row = row0 + wm + mi * 16 + fq * 4 + r;
      bf16_t* Cp = C + (size_t)row * N + col0 + wn + fr;
#pragma unroll
      for (int ni = 0; ni < 4; ni++) Cp[ni * 16] = f2bf(acc[mi][ni][r]);
    }
  }
}

// ---------------- GEMM (out-proj): C[M,n](f32) = AO[M,K](bf16) * Wo[n,K]^T(f32)
// A staged via verified DMA (verbatim R13); B reg-cvt staged (as above).
__global__ __launch_bounds__(256)
void gemm_out_kernel(const bf16_t* __restrict__ A, const float* __restrict__ Wo,
                     float* __restrict__ C, int M, int N, int K, int nbx) {
  __shared__ __align__(16) bf16_t lA[2][128 * 32];
  __shared__ __align__(16) bf16_t lB[2][128 * 32];
  const int t = threadIdx.x;
  const int lane = t & 63, wave = t >> 6;

  const int nwg = gridDim.x;
  const int orig = blockIdx.x;
  const int xcd = orig & 7;
  const int qq = nwg >> 3, rr = nwg & 7;
  const int base = (xcd < rr) ? xcd * (qq + 1) : rr * (qq + 1) + (xcd - rr) * qq;
  const int wgid = base + (orig >> 3);
  const int row0 = (wgid / nbx) * 128, col0 = (wgid % nbx) * 128;

  const int wm = (wave >> 1) * 64, wn = (wave & 1) * 64;

  const int rA = wave * 32 + (lane >> 2);
  const int cA = (lane & 3) * 8;            // bf16 elements (16B) -- verbatim R8
  const int cE = (lane & 3) * 8;            // f32 elements for B
  const char* Asrc0 = (const char*)(A + (size_t)(row0 + rA) * K + cA);
  const char* Asrc1 = (const char*)(A + (size_t)(row0 + rA + 16) * K + cA);
  const float* Bs0 = Wo + (size_t)(col0 + rA) * K + cE;
  const float* Bs1 = Wo + (size_t)(col0 + rA + 16) * K + cE;

  const int fr = lane & 15, fq = lane >> 4;
  f32x4 acc[4][4] = {};

  auto ld4 = [&](const float* p) { return *reinterpret_cast<const float4*>(p); };
  auto wrB = [&](int b, int off, bf16x8 v) {
    *reinterpret_cast<bf16x8*>((char*)lB[b] + wave * 2048 + off + lane * 16) = v;
  };
  auto stageA = [&](int b, int k0) {
    const size_t kb = (size_t)k0 * 2;
    char* lAd = (char*)lA[b] + wave * 2048;
    load_lds16(Asrc0 + kb, lAd);
    load_lds16(Asrc1 + kb, lAd + 1024);
  };

  // prologue: tile 0
  stageA(0, 0);
  wrB(0, 0,    cvt8(ld4(Bs0), ld4(Bs0 + 4)));
  wrB(0, 1024, cvt8(ld4(Bs1), ld4(Bs1 + 4)));

  int b = 0;
  for (int k0 = 0; k0 < K; k0 += 32) {
    __syncthreads();
    const bool more = (k0 + 32 < K);
    float4 b00, b01, b10, b11;
    if (more) {
      stageA(b ^ 1, k0 + 32);               // DMA fire-and-forget (verified path)
      const int e = k0 + 32;
      b00 = ld4(Bs0 + e); b01 = ld4(Bs0 + e + 4);
      b10 = ld4(Bs1 + e); b11 = ld4(Bs1 + e + 4);
    }

    bf16x8 af[4], bfv[4];
#pragma unroll
    for (int mi = 0; mi < 4; mi++)
      af[mi] = *reinterpret_cast<const bf16x8*>(&lA[b][(wm + mi * 16 + fr) * 32 + fq * 8]);
#pragma unroll
    for (int ni = 0; ni < 4; ni++)
      bfv[ni] = *reinterpret_cast<const bf16x8*>(&lB[b][(wn + ni * 16 + fr) * 32 + fq * 8]);
    __builtin_amdgcn_s_setprio(1);
#pragma unroll
    for (int mi = 0; mi < 4; mi++)
#pragma unroll
      for (int ni = 0; ni < 4; ni++)
        acc[mi][ni] = __builtin_amdgcn_mfma_f32_16x16x32_bf16(af[mi], bfv[ni], acc[mi][ni], 0, 0, 0);
    __builtin_amdgcn_s_setprio(0);

    if (more) {
      wrB(b ^ 1, 0,    cvt8(b00, b01));
      wrB(b ^ 1, 1024, cvt8(b10, b11));
    }
    b ^= 1;
  }

#pragma unroll
  for (int mi = 0; mi < 4; mi++) {
#pragma unroll
    for (int r = 0; r < 4; r++) {
      int row = row0 + wm + mi * 16 + fq * 4 + r;
      float* Cp = C + (size_t)row * N + col0 + wn + fr;
#pragma unroll
      for (int ni = 0; ni < 4; ni++) Cp[ni * 16] = acc[mi][ni][r];
    }
  }
}

// ---------------- RoPE, Q and K in one launch (40 heads) ----------------
__global__ void rope_all_kernel(bf16_t* __restrict__ qkv, float qscale) {
  int idx = blockIdx.x * blockDim.x + threadIdx.x;  // total = S * 40 * 64
  int i = idx & 63;
  int hh = (idx >> 6) % (NH + NKV);
  int s = idx / (64 * (NH + NKV));
  const float NEG_LOG1E4_64 = -0.14391156f;  // -ln(10000)/64
  float freq = __expf((float)i * NEG_LOG1E4_64);
  float ang = (float)s * freq;
  float sn, cs;
  __sincosf(ang, &sn, &cs);
  const int colbase = (hh < NH) ? hh * DH : HD + (hh - NH) * DH;
  const float scale = (hh < NH) ? qscale : 1.0f;
  bf16_t* p = qkv + (size_t)s * NQKV + colbase;
  float x1 = bf2f(p[i]);
  float x2 = bf2f(p[i + 64]);
  p[i]      = f2bf((x1 * cs - x2 * sn) * scale);
  p[i + 64] = f2bf((x2 * cs + x1 * sn) * scale);
}

// ---------------- transpose [R][C] -> [C][R] (bf16), strided input ----------------
__global__ void transpose_kernel(const bf16_t* __restrict__ in, bf16_t* __restrict__ out,
                                 int R, int C, int in_rstride) {
  __shared__ bf16_t tile[64][65];
  int c0 = blockIdx.x * 64, r0 = blockIdx.y * 64;
  int t = threadIdx.x;
#pragma unroll
  for (int i = 0; i < 16; i++) {
    int idx = t + i * 256;
    int r = idx >> 6, c = idx & 63;
    tile[r][c] = in[(size_t)(r0 + r) * in_rstride + c0 + c];
  }
  __syncthreads();
#pragma unroll
  for (int i = 0; i < 16; i++) {
    int idx = t + i * 256;
    int r = idx >> 6, c = idx & 63;
    out[(size_t)(c0 + r) * R + r0 + c] = tile[c][r];
  }
}

// ---------------- flash attention (causal, GQA) ----------------
__global__ __launch_bounds__(256)
void attn_kernel(const bf16_t* __restrict__ Qkv, const bf16_t* __restrict__ Vt,
                 bf16_t* __restrict__ O) {
  __shared__ __align__(16) char lK[2][64 * 256];   // 16 KB x2
  __shared__ __align__(16) char lV[2][64 * 256];   // 16 KB x2
  __shared__ __align__(16) bf16_t lP[4][16 * 72];  // 9216 B

  const int t = threadIdx.x, lane = t & 63, wave = t >> 6;
  const int h = blockIdx.y, kvh = h >> 2;
  const int pid = blockIdx.x;                      // 0..15
  const int fr = lane & 15, fq = lane >> 4;

  const int gc = wave * 4 + (lane >> 4);
  const int sS = (lane & 15) ^ (gc & 15);
  const char* KsrcB = (const char*)(Qkv + HD + (size_t)kvh * DH) +
                      (size_t)gc * QKV_STRIDE_B + sS * 16;
  const int dVc = gc * 2 + (sS >> 3);
  const char* VsrcB = (const char*)Vt + (size_t)kvh * DH * S_LEN * 2 +
                      (size_t)dVc * 4096 + (sS & 7) * 16;
  char* dKw = (char*)lK[0] + wave * 1024;
  char* dVw = (char*)lV[0] + wave * 1024;

  auto stage = [&](int buf, int kv0) {
    char* dk = dKw + buf * (64 * 256);
    char* dv = dVw + buf * (64 * 256);
    const char* ks = KsrcB + (size_t)kv0 * QKV_STRIDE_B;
    const char* vs = VsrcB + (size_t)kv0 * 2;
#pragma unroll
    for (int i = 0; i < 4; i++) {
      load_lds16(ks + i * (16 * QKV_STRIDE_B), dk + i * 4096);
      load_lds16(vs + i * (size_t)(32 * 4096), dv + i * 4096);
    }
  };

  stage(0, 0);
  int buf = 0;

  for (int pass = 0; pass < 2; pass++) {
    const int qb = pass ? pid : (31 - pid);        // long block first
    const int q0 = qb * 64 + wave * 16;

    bf16x8 qf[4];
    const bf16_t* Qp = Qkv + (size_t)(q0 + fr) * NQKV + h * DH + fq * 8;
#pragma unroll
    for (int kt = 0; kt < 4; kt++)
      qf[kt] = *reinterpret_cast<const bf16x8*>(Qp + kt * 32);

    f32x4 o_acc[8] = {};
    float m_run[4] = {-1e30f, -1e30f, -1e30f, -1e30f};
    float l_run[4] = {0.f, 0.f, 0.f, 0.f};

    for (int tt = 0; tt <= qb; tt++) {
      __syncthreads();
      if (tt < qb)            stage(buf ^ 1, (tt + 1) * 64);
      else if (pass == 0)     stage(buf ^ 1, 0);

      const char* cK = lK[buf];
      const char* cV = lV[buf];
      const bool diag = (tt == qb);

      f32x4 s_acc[4] = {};
      __builtin_amdgcn_s_setprio(1);
#pragma unroll
      for (int nt = 0; nt < 4; nt++) {
        const char* rowp = cK + (nt * 16 + fr) * 256;
#pragma unroll
        for (int kt = 0; kt < 4; kt++) {
          const bf16x8 kf = *reinterpret_cast<const bf16x8*>(
              rowp + (((kt * 4 + fq) ^ fr) << 4));
          s_acc[nt] = __builtin_amdgcn_mfma_f32_16x16x32_bf16(qf[kt], kf, s_acc[nt], 0, 0, 0);
        }
      }
      __builtin_amdgcn_s_setprio(0);

      float pmax[4];
#pragma unroll
      for (int r = 0; r < 4; r++) {
        if (diag) {
          const int qrel = wave * 16 + fq * 4 + r;
#pragma unroll
          for (int nt = 0; nt < 4; nt++)
            if (nt * 16 + fr > qrel) s_acc[nt][r] = -1e30f;
        }
        float mr = fmaxf(fmaxf(s_acc[0][r], s_acc[1][r]), fmaxf(s_acc[2][r], s_acc[3][r]));
#pragma unroll
        for (int off = 1; off < 16; off <<= 1) mr = fmaxf(mr, __shfl_xor(mr, off, 16));
        pmax[r] = mr;
      }
      bool nb = (pmax[0] > m_run[0] + 8.f) || (pmax[1] > m_run[1] + 8.f) ||
                (pmax[2] > m_run[2] + 8.f) || (pmax[3] > m_run[3] + 8.f);
      if (__any(nb)) {
#pragma unroll
        for (int r = 0; r < 4; r++) {
          float mnew = fmaxf(m_run[r], pmax[r]);
          float alpha = __expf(m_run[r] - mnew);
#pragma unroll
          for (int ni = 0; ni < 8; ni++) o_acc[ni][r] *= alpha;
          l_run[r] *= alpha;
          m_run[r] = mnew;
        }
      }
      bf16_t* lPw = lP[wave];
#pragma unroll
      for (int r = 0; r < 4; r++) {
        float p0 = __expf(s_acc[0][r] - m_run[r]);
        float p1 = __expf(s_acc[1][r] - m_run[r]);
        float p2 = __expf(s_acc[2][r] - m_run[r]);
        float p3 = __expf(s_acc[3][r] - m_run[r]);
        float sr = (p0 + p1) + (p2 + p3);
#pragma unroll
        for (int off = 1; off < 16; off <<= 1) sr += __shfl_xor(sr, off, 16);
        l_run[r] += sr;
        const int row = fq * 4 + r;
        lPw[row * 72 + fr]      = f2bf(p0);
        lPw[row * 72 + 16 + fr] = f2bf(p1);
        lPw[row * 72 + 32 + fr] = f2bf(p2);
        lPw[row * 72 + 48 + fr] = f2bf(p3);
      }

#pragma unroll
      for (int kk = 0; kk < 2; kk++) {
        const bf16x8 pf = *reinterpret_cast<const bf16x8*>(lPw + fr * 72 + kk * 32 + fq * 8);
        __builtin_amdgcn_s_setprio(1);
#pragma unroll
        for (int ni = 0; ni < 8; ni++) {
          const int d = ni * 16 + fr;
          const int g = d >> 1;
          const int slot = ((d & 1) * 8 + kk * 4 + fq) ^ (g & 15);
          const bf16x8 vf = *reinterpret_cast<const bf16x8*>(cV + g * 256 + (slot << 4));
          o_acc[ni] = __builtin_amdgcn_mfma_f32_16x16x32_bf16(pf, vf, o_acc[ni], 0, 0, 0);
        }
        __builtin_amdgcn_s_setprio(0);
      }
      buf ^= 1;
    }

#pragma unroll
    for (int r = 0; r < 4; r++) {
      int qrow = q0 + fq * 4 + r;
      float inv = 1.0f / l_run[r];
      bf16_t* Op = O + ((size_t)qrow * NH + h) * DH + fr;
#pragma unroll
      for (int ni = 0; ni < 8; ni++) Op[ni * 16] = f2bf(o_acc[ni][r] * inv);
    }
  }
}

// ---------------- launch ----------------
extern "C" void kernel_launch(void* const* d_in, const int* in_sizes, int n_in,
                              void* d_out, int out_size, void* d_ws, size_t ws_size,
                              hipStream_t stream) {
  const float* X  = (const float*)d_in[0];
  const float* Wq = (const float*)d_in[1];
  const float* Wk = (const float*)d_in[2];
  const float* Wv = (const float*)d_in[3];
  const float* Wo = (const float*)d_in[4];
  float* out = (float*)d_out;

  char* ws = (char*)d_ws;
  size_t off = 0;
  auto alloc = [&](size_t bytes) {
    char* p = ws + off;
    off += (bytes + 255) & ~(size_t)255;
    return p;
  };
  const size_t kvdim = (size_t)NKV * DH;           // 1024
  bf16_t* QKVb = (bf16_t*)alloc((size_t)S_LEN * NQKV * 2);   // [2048][6144]
  bf16_t* Vtb  = (bf16_t*)alloc((size_t)S_LEN * kvdim * 2);  // [1024][2048]
  bf16_t* AOb  = (bf16_t*)alloc((size_t)S_LEN * HD * 2);
  (void)ws_size;

  // fused QKV projection (cvt folded in): [2048][6144]
  {
    int nbx = NQKV / 128, nby = S_LEN / 128;
    gemm_qkv_kernel<<<dim3(nbx * nby), dim3(256), 0, stream>>>(
        X, Wq, Wk, Wv, QKVb, S_LEN, NQKV, HD, nbx);
  }

  // RoPE, Q (scaled by 1/sqrt(128)) and K in one launch
  rope_all_kernel<<<dim3(S_LEN * (NH + NKV) * 64 / 256), dim3(256), 0, stream>>>(
      QKVb, 0.08838834764831845f);

  // V^T ([1024][2048]) from V slice at col 5120
  transpose_kernel<<<dim3((int)kvdim / 64, S_LEN / 64), dim3(256), 0, stream>>>(
      QKVb + HD + kvdim, Vtb, S_LEN, (int)kvdim, NQKV);

  // attention (paired causal blocks: perfect balance)
  attn_kernel<<<dim3(16, NH), dim3(256), 0, stream>>>(QKVb, Vtb, AOb);

  // output projection (cvt of Wo folded in, f32 out)
  {
    int nbx = HD / 128, nby = S_LEN / 128;
    gemm_out_kernel<<<dim3(nbx * nby), dim3(256), 0, stream>>>(
        AOb, Wo, out, S_LEN, HD, HD, nbx);
  }
}

// Round 17
// 359.678 us; speedup vs baseline: 1.5153x; 1.5153x over previous
//
#include <hip/hip_runtime.h>

// ---------------- problem constants ----------------
#define S_LEN 2048
#define HD    4096
#define NH    32
#define NKV   8
#define DH    128
#define NQKV  6144          // 4096 Q + 1024 K + 1024 V
#define QKV_STRIDE_B (NQKV * 2)

typedef __bf16 bf16_t;
typedef __bf16 bf16x8 __attribute__((ext_vector_type(8)));
typedef float  f32x4  __attribute__((ext_vector_type(4)));
typedef unsigned short ushort8v __attribute__((ext_vector_type(8)));

// ---------------- helpers ----------------
__device__ inline unsigned short f2bf_bits(float f) {
  unsigned int u = __builtin_bit_cast(unsigned int, f);
  unsigned int r = (u + 0x7FFFu + ((u >> 16) & 1u)) >> 16;  // RNE
  return (unsigned short)r;
}
__device__ inline bf16_t f2bf(float f) {
  return __builtin_bit_cast(bf16_t, f2bf_bits(f));
}
__device__ inline float bf2f(bf16_t b) {
  unsigned int u = ((unsigned int)__builtin_bit_cast(unsigned short, b)) << 16;
  return __builtin_bit_cast(float, u);
}

__device__ inline void load_lds16(const void* g, void* l) {
  __builtin_amdgcn_global_load_lds(
      (__attribute__((address_space(1))) unsigned int*)(void*)g,
      (__attribute__((address_space(3))) unsigned int*)l, 16, 0, 0);
}

__device__ inline void store_out(float* p, float v)  { *p = v; }
__device__ inline void store_out(bf16_t* p, float v) { *p = f2bf(v); }

// ---------------- fused f32 -> bf16 convert, all 5 tensors in one launch ------
// dst regions (Xb | Wqkvb=[Wq|Wk|Wv] | Wob) are CONTIGUOUS in ws by construction,
// so global n8-index i maps directly to dst; source chosen by segment.
__global__ void cvt_all_kernel(const float* __restrict__ s0, const float* __restrict__ s1,
                               const float* __restrict__ s2, const float* __restrict__ s3,
                               const float* __restrict__ s4,
                               long n0, long n1, long n2, long n3,
                               long total, bf16_t* __restrict__ dst) {
  long stride = (long)gridDim.x * blockDim.x;
  for (long i = (long)blockIdx.x * blockDim.x + threadIdx.x; i < total; i += stride) {
    const float* src;
    long rel = i;
    if (rel < n0) src = s0;
    else {
      rel -= n0;
      if (rel < n1) src = s1;
      else {
        rel -= n1;
        if (rel < n2) src = s2;
        else {
          rel -= n2;
          if (rel < n3) src = s3;
          else { rel -= n3; src = s4; }
        }
      }
    }
    float4 v0 = reinterpret_cast<const float4*>(src)[rel * 2];
    float4 v1 = reinterpret_cast<const float4*>(src)[rel * 2 + 1];
    ushort8v o;
    o[0] = f2bf_bits(v0.x); o[1] = f2bf_bits(v0.y);
    o[2] = f2bf_bits(v0.z); o[3] = f2bf_bits(v0.w);
    o[4] = f2bf_bits(v1.x); o[5] = f2bf_bits(v1.y);
    o[6] = f2bf_bits(v1.z); o[7] = f2bf_bits(v1.w);
    reinterpret_cast<ushort8v*>(dst)[i] = o;
  }
}

// ---------------- GEMM: C[M,N] = A[M,K] * B[N,K]^T ----------------
// R12's verified dbuf pipeline at BK=32. LDS 32 KiB = {lA,lB} x 2 buffers.
// Per 32-K step: sync -> stage(T+1 into buf^1) -> reads(buf) -> 16 MFMA -> flip.
// All address expressions verbatim R8 (the only arithmetic proven on HW).
// Safety at each __syncthreads: vmcnt(0) => buf's DMA landed; lgkmcnt(0)+barrier
// => all reads of buf^1 serviced, so staging into buf^1 after the sync is safe.
template <typename OutT>
__global__ __launch_bounds__(256)
void gemm_db32_kernel(const bf16_t* __restrict__ A, const bf16_t* __restrict__ B,
                      OutT* __restrict__ C, int M, int N, int K, int nbx) {
  __shared__ __align__(16) bf16_t lA[2][128 * 32];
  __shared__ __align__(16) bf16_t lB[2][128 * 32];
  const int t = threadIdx.x;
  const int lane = t & 63, wave = t >> 6;

  // bijective XCD-aware remap (verbatim R8)
  const int nwg = gridDim.x;
  const int orig = blockIdx.x;
  const int xcd = orig & 7;
  const int qq = nwg >> 3, rr = nwg & 7;
  const int base = (xcd < rr) ? xcd * (qq + 1) : rr * (qq + 1) + (xcd - rr) * qq;
  const int wgid = base + (orig >> 3);
  const int row0 = (wgid / nbx) * 128, col0 = (wgid % nbx) * 128;

  const int wm = (wave >> 1) * 64, wn = (wave & 1) * 64;

  // staging geometry (verbatim R8)
  const int rA = wave * 32 + (lane >> 2);
  const int cA = (lane & 3) * 8;
  const char* Asrc0 = (const char*)(A + (size_t)(row0 + rA) * K + cA);
  const char* Asrc1 = (const char*)(A + (size_t)(row0 + rA + 16) * K + cA);
  const char* Bsrc0 = (const char*)(B + (size_t)(col0 + rA) * K + cA);
  const char* Bsrc1 = (const char*)(B + (size_t)(col0 + rA + 16) * K + cA);

  const int fr = lane & 15, fq = lane >> 4;
  f32x4 acc[4][4] = {};

  auto stage = [&](int b, int k0) {
    const size_t kb = (size_t)k0 * 2;
    char* lAd = (char*)lA[b] + wave * 2048;
    char* lBd = (char*)lB[b] + wave * 2048;
    load_lds16(Asrc0 + kb, lAd);
    load_lds16(Asrc1 + kb, lAd + 1024);
    load_lds16(Bsrc0 + kb, lBd);
    load_lds16(Bsrc1 + kb, lBd + 1024);
  };

  stage(0, 0);
  int b = 0;
  for (int k0 = 0; k0 < K; k0 += 32) {
    __syncthreads();   // vmcnt(0)+lgkmcnt(0)+barrier: buf landed; buf^1 readers done
    if (k0 + 32 < K) stage(b ^ 1, k0 + 32);   // overlapped with this step's compute

    bf16x8 af[4], bfv[4];
#pragma unroll
    for (int mi = 0; mi < 4; mi++)
      af[mi] = *reinterpret_cast<const bf16x8*>(&lA[b][(wm + mi * 16 + fr) * 32 + fq * 8]);
#pragma unroll
    for (int ni = 0; ni < 4; ni++)
      bfv[ni] = *reinterpret_cast<const bf16x8*>(&lB[b][(wn + ni * 16 + fr) * 32 + fq * 8]);
    __builtin_amdgcn_s_setprio(1);
#pragma unroll
    for (int mi = 0; mi < 4; mi++)
#pragma unroll
      for (int ni = 0; ni < 4; ni++)
        acc[mi][ni] = __builtin_amdgcn_mfma_f32_16x16x32_bf16(af[mi], bfv[ni], acc[mi][ni], 0, 0, 0);
    __builtin_amdgcn_s_setprio(0);
    b ^= 1;
  }

  // epilogue (verbatim R8)
#pragma unroll
  for (int mi = 0; mi < 4; mi++) {
#pragma unroll
    for (int r = 0; r < 4; r++) {
      int row = row0 + wm + mi * 16 + fq * 4 + r;
      OutT* Cp = C + (size_t)row * N + col0 + wn + fr;
#pragma unroll
      for (int ni = 0; ni < 4; ni++) store_out(Cp + ni * 16, acc[mi][ni][r]);
    }
  }
}

// ---------------- RoPE, Q and K in one launch (40 heads) ----------------
__global__ void rope_all_kernel(bf16_t* __restrict__ qkv, float qscale) {
  int idx = blockIdx.x * blockDim.x + threadIdx.x;  // total = S * 40 * 64
  int i = idx & 63;
  int hh = (idx >> 6) % (NH + NKV);
  int s = idx / (64 * (NH + NKV));
  const float NEG_LOG1E4_64 = -0.14391156f;  // -ln(10000)/64
  float freq = __expf((float)i * NEG_LOG1E4_64);
  float ang = (float)s * freq;
  float sn, cs;
  __sincosf(ang, &sn, &cs);
  const int colbase = (hh < NH) ? hh * DH : HD + (hh - NH) * DH;
  const float scale = (hh < NH) ? qscale : 1.0f;
  bf16_t* p = qkv + (size_t)s * NQKV + colbase;
  float x1 = bf2f(p[i]);
  float x2 = bf2f(p[i + 64]);
  p[i]      = f2bf((x1 * cs - x2 * sn) * scale);
  p[i + 64] = f2bf((x2 * cs + x1 * sn) * scale);
}

// ---------------- transpose [R][C] -> [C][R] (bf16), strided input ----------------
__global__ void transpose_kernel(const bf16_t* __restrict__ in, bf16_t* __restrict__ out,
                                 int R, int C, int in_rstride) {
  __shared__ bf16_t tile[64][65];
  int c0 = blockIdx.x * 64, r0 = blockIdx.y * 64;
  int t = threadIdx.x;
#pragma unroll
  for (int i = 0; i < 16; i++) {
    int idx = t + i * 256;
    int r = idx >> 6, c = idx & 63;
    tile[r][c] = in[(size_t)(r0 + r) * in_rstride + c0 + c];
  }
  __syncthreads();
#pragma unroll
  for (int i = 0; i < 16; i++) {
    int idx = t + i * 256;
    int r = idx >> 6, c = idx & 63;
    out[(size_t)(c0 + r) * R + r0 + c] = tile[c][r];
  }
}

// ---------------- flash attention (causal, GQA) ----------------
// grid (16, NH): workgroup p handles Q-blocks {31-p, p} -> exactly 33 KV-tiles
// each (perfect balance; 512 blocks = 2/CU, all resident). 256 threads = 4 waves.
// KVBLK=64, K+V double-buffered LDS, one barrier/tile; XOR-swizzle slot^=(row&15)
// via pre-swizzled global source. P roundtrip via lP[16][72].
__global__ __launch_bounds__(256)
void attn_kernel(const bf16_t* __restrict__ Qkv, const bf16_t* __restrict__ Vt,
                 bf16_t* __restrict__ O) {
  __shared__ __align__(16) char lK[2][64 * 256];   // 16 KB x2
  __shared__ __align__(16) char lV[2][64 * 256];   // 16 KB x2
  __shared__ __align__(16) bf16_t lP[4][16 * 72];  // 9216 B

  const int t = threadIdx.x, lane = t & 63, wave = t >> 6;
  const int h = blockIdx.y, kvh = h >> 2;
  const int pid = blockIdx.x;                      // 0..15
  const int fr = lane & 15, fq = lane >> 4;

  const int gc = wave * 4 + (lane >> 4);
  const int sS = (lane & 15) ^ (gc & 15);
  const char* KsrcB = (const char*)(Qkv + HD + (size_t)kvh * DH) +
                      (size_t)gc * QKV_STRIDE_B + sS * 16;
  const int dVc = gc * 2 + (sS >> 3);
  const char* VsrcB = (const char*)Vt + (size_t)kvh * DH * S_LEN * 2 +
                      (size_t)dVc * 4096 + (sS & 7) * 16;
  char* dKw = (char*)lK[0] + wave * 1024;
  char* dVw = (char*)lV[0] + wave * 1024;

  auto stage = [&](int buf, int kv0) {
    char* dk = dKw + buf * (64 * 256);
    char* dv = dVw + buf * (64 * 256);
    const char* ks = KsrcB + (size_t)kv0 * QKV_STRIDE_B;
    const char* vs = VsrcB + (size_t)kv0 * 2;
#pragma unroll
    for (int i = 0; i < 4; i++) {
      load_lds16(ks + i * (16 * QKV_STRIDE_B), dk + i * 4096);
      load_lds16(vs + i * (size_t)(32 * 4096), dv + i * 4096);
    }
  };

  stage(0, 0);
  int buf = 0;

  for (int pass = 0; pass < 2; pass++) {
    const int qb = pass ? pid : (31 - pid);        // long block first
    const int q0 = qb * 64 + wave * 16;

    bf16x8 qf[4];
    const bf16_t* Qp = Qkv + (size_t)(q0 + fr) * NQKV + h * DH + fq * 8;
#pragma unroll
    for (int kt = 0; kt < 4; kt++)
      qf[kt] = *reinterpret_cast<const bf16x8*>(Qp + kt * 32);

    f32x4 o_acc[8] = {};
    float m_run[4] = {-1e30f, -1e30f, -1e30f, -1e30f};
    float l_run[4] = {0.f, 0.f, 0.f, 0.f};

    for (int tt = 0; tt <= qb; tt++) {
      __syncthreads();  // implicit vmcnt(0): prefetch landed; prev compute done
      if (tt < qb)            stage(buf ^ 1, (tt + 1) * 64);
      else if (pass == 0)     stage(buf ^ 1, 0);   // pass-B tile 0

      const char* cK = lK[buf];
      const char* cV = lV[buf];
      const bool diag = (tt == qb);

      // ---- S = Q K^T : 16 MFMA ----
      f32x4 s_acc[4] = {};
      __builtin_amdgcn_s_setprio(1);
#pragma unroll
      for (int nt = 0; nt < 4; nt++) {
        const char* rowp = cK + (nt * 16 + fr) * 256;
#pragma unroll
        for (int kt = 0; kt < 4; kt++) {
          const bf16x8 kf = *reinterpret_cast<const bf16x8*>(
              rowp + (((kt * 4 + fq) ^ fr) << 4));
          s_acc[nt] = __builtin_amdgcn_mfma_f32_16x16x32_bf16(qf[kt], kf, s_acc[nt], 0, 0, 0);
        }
      }
      __builtin_amdgcn_s_setprio(0);

      // ---- online softmax, defer-max (THR=8) ----
      float pmax[4];
#pragma unroll
      for (int r = 0; r < 4; r++) {
        if (diag) {
          const int qrel = wave * 16 + fq * 4 + r;
#pragma unroll
          for (int nt = 0; nt < 4; nt++)
            if (nt * 16 + fr > qrel) s_acc[nt][r] = -1e30f;
        }
        float mr = fmaxf(fmaxf(s_acc[0][r], s_acc[1][r]), fmaxf(s_acc[2][r], s_acc[3][r]));
#pragma unroll
        for (int off = 1; off < 16; off <<= 1) mr = fmaxf(mr, __shfl_xor(mr, off, 16));
        pmax[r] = mr;
      }
      bool nb = (pmax[0] > m_run[0] + 8.f) || (pmax[1] > m_run[1] + 8.f) ||
                (pmax[2] > m_run[2] + 8.f) || (pmax[3] > m_run[3] + 8.f);
      if (__any(nb)) {
#pragma unroll
        for (int r = 0; r < 4; r++) {
          float mnew = fmaxf(m_run[r], pmax[r]);
          float alpha = __expf(m_run[r] - mnew);
#pragma unroll
          for (int ni = 0; ni < 8; ni++) o_acc[ni][r] *= alpha;
          l_run[r] *= alpha;
          m_run[r] = mnew;
        }
      }
      bf16_t* lPw = lP[wave];
#pragma unroll
      for (int r = 0; r < 4; r++) {
        float p0 = __expf(s_acc[0][r] - m_run[r]);
        float p1 = __expf(s_acc[1][r] - m_run[r]);
        float p2 = __expf(s_acc[2][r] - m_run[r]);
        float p3 = __expf(s_acc[3][r] - m_run[r]);
        float sr = (p0 + p1) + (p2 + p3);
#pragma unroll
        for (int off = 1; off < 16; off <<= 1) sr += __shfl_xor(sr, off, 16);
        l_run[r] += sr;
        const int row = fq * 4 + r;
        lPw[row * 72 + fr]      = f2bf(p0);
        lPw[row * 72 + 16 + fr] = f2bf(p1);
        lPw[row * 72 + 32 + fr] = f2bf(p2);
        lPw[row * 72 + 48 + fr] = f2bf(p3);
      }

      // ---- O += P V : 16 MFMA ----
#pragma unroll
      for (int kk = 0; kk < 2; kk++) {
        const bf16x8 pf = *reinterpret_cast<const bf16x8*>(lPw + fr * 72 + kk * 32 + fq * 8);
        __builtin_amdgcn_s_setprio(1);
#pragma unroll
        for (int ni = 0; ni < 8; ni++) {
          const int d = ni * 16 + fr;
          const int g = d >> 1;
          const int slot = ((d & 1) * 8 + kk * 4 + fq) ^ (g & 15);
          const bf16x8 vf = *reinterpret_cast<const bf16x8*>(cV + g * 256 + (slot << 4));
          o_acc[ni] = __builtin_amdgcn_mfma_f32_16x16x32_bf16(pf, vf, o_acc[ni], 0, 0, 0);
        }
        __builtin_amdgcn_s_setprio(0);
      }
      buf ^= 1;
    }

    // ---- epilogue: normalize and store this pass's rows ----
#pragma unroll
    for (int r = 0; r < 4; r++) {
      int qrow = q0 + fq * 4 + r;
      float inv = 1.0f / l_run[r];
      bf16_t* Op = O + ((size_t)qrow * NH + h) * DH + fr;
#pragma unroll
      for (int ni = 0; ni < 8; ni++) Op[ni * 16] = f2bf(o_acc[ni][r] * inv);
    }
  }
}

// ---------------- launch ----------------
extern "C" void kernel_launch(void* const* d_in, const int* in_sizes, int n_in,
                              void* d_out, int out_size, void* d_ws, size_t ws_size,
                              hipStream_t stream) {
  const float* X  = (const float*)d_in[0];
  const float* Wq = (const float*)d_in[1];
  const float* Wk = (const float*)d_in[2];
  const float* Wv = (const float*)d_in[3];
  const float* Wo = (const float*)d_in[4];
  float* out = (float*)d_out;

  char* ws = (char*)d_ws;
  size_t off = 0;
  auto alloc = [&](size_t bytes) {
    char* p = ws + off;
    off += (bytes + 255) & ~(size_t)255;
    return p;
  };
  const size_t kvdim = (size_t)NKV * DH;           // 1024
  // NOTE: Xb, Wqkvb, Wob must stay contiguous in this order (cvt_all relies on it;
  // all three sizes are multiples of 256 so alloc() introduces no gaps).
  bf16_t* Xb    = (bf16_t*)alloc((size_t)S_LEN * HD * 2);
  bf16_t* Wqkvb = (bf16_t*)alloc((size_t)NQKV * HD * 2);   // [6144][4096]
  bf16_t* Wob   = (bf16_t*)alloc((size_t)HD * HD * 2);
  bf16_t* QKVb  = (bf16_t*)alloc((size_t)S_LEN * NQKV * 2);  // [2048][6144]
  bf16_t* Vtb   = (bf16_t*)alloc((size_t)S_LEN * kvdim * 2); // [1024][2048]
  bf16_t* AOb   = (bf16_t*)alloc((size_t)S_LEN * HD * 2);
  (void)ws_size;

  // fused conversion: segments in dst-linear order X | Wq | Wk | Wv | Wo
  {
    const long n0 = (long)S_LEN * HD / 8;          // X
    const long n1 = (long)HD * HD / 8;             // Wq
    const long n2 = (long)kvdim * HD / 8;          // Wk
    const long n3 = (long)kvdim * HD / 8;          // Wv
    const long n4 = (long)HD * HD / 8;             // Wo
    const long total = n0 + n1 + n2 + n3 + n4;
    cvt_all_kernel<<<dim3(2048), dim3(256), 0, stream>>>(
        X, Wq, Wk, Wv, Wo, n0, n1, n2, n3, total, Xb);
  }

  // fused QKV projection: [2048][6144]
  {
    int nbx = NQKV / 128, nby = S_LEN / 128;
    gemm_db32_kernel<bf16_t><<<dim3(nbx * nby), dim3(256), 0, stream>>>(
        Xb, Wqkvb, QKVb, S_LEN, NQKV, HD, nbx);
  }

  // RoPE, Q (scaled by 1/sqrt(128)) and K in one launch
  rope_all_kernel<<<dim3(S_LEN * (NH + NKV) * 64 / 256), dim3(256), 0, stream>>>(
      QKVb, 0.08838834764831845f);

  // V^T ([1024][2048]) from V slice at col 5120
  transpose_kernel<<<dim3((int)kvdim / 64, S_LEN / 64), dim3(256), 0, stream>>>(
      QKVb + HD + kvdim, Vtb, S_LEN, (int)kvdim, NQKV);

  // attention (paired causal blocks: perfect balance)
  attn_kernel<<<dim3(16, NH), dim3(256), 0, stream>>>(QKVb, Vtb, AOb);

  // output projection (f32 out)
  {
    int nbx = HD / 128, nby = S_LEN / 128;
    gemm_db32_kernel<float><<<dim3(nbx * nby), dim3(256), 0, stream>>>(
        AOb, Wob, out, S_LEN, HD, HD, nbx);
  }
}